// Round 17
// baseline (142.559 us; speedup 1.0000x reference)
//
#include <hip/hip_runtime.h>
#include <hip/hip_fp16.h>

#define F_IN 128
#define HID 128
#define HID4 32
#define NPB 256          // nodes per CSR bucket
#define SRC_BITS 17      // n_nodes = 50000 < 2^17
#define NBK 256          // partition chunks/blocks (== 256 so partial idx == bucket idx)
#define MAXBUCKET 256    // LDS counter array size (n_buckets = 196)

static inline size_t alignup(size_t x) { return (x + 255) & ~(size_t)255; }

typedef _Float16 half8 __attribute__((ext_vector_type(8)));
typedef float f32x4 __attribute__((ext_vector_type(4)));

union F4H8 { float4 f; __half2 h[4]; };   // 8 halfs = 16 B
union U2H4 { uint2 u; _Float16 h[4]; };   // 4 halfs = 8 B

// ---------------- pass 1: bucket histogram (+ folded W1 transpose to fp16) ----------------

__global__ __launch_bounds__(1024) void hist_k(const int* __restrict__ dst,
                                               int* __restrict__ ghist,
                                               const float* __restrict__ W1,
                                               _Float16* __restrict__ Wt,
                                               int ne, int n_buckets) {
    __shared__ int h[MAXBUCKET];
    const int t = threadIdx.x;
    if (blockIdx.x < 16) {
        int q = blockIdx.x * 1024 + t;
        int k = q >> 7, n = q & 127;
        Wt[n * 128 + k] = (_Float16)W1[q];
    }
    for (int b = t; b < n_buckets; b += 1024) h[b] = 0;
    __syncthreads();
    const int chunk = (ne + NBK - 1) / NBK;
    const int beg = blockIdx.x * chunk;
    const int end = min(ne, beg + chunk);
    for (int e = beg + t; e < end; e += 1024)
        atomicAdd(&h[dst[e] / NPB], 1);
    __syncthreads();
    for (int b = t; b < n_buckets; b += 1024)
        ghist[(size_t)b * NBK + blockIdx.x] = h[b];
}

// ---------------- 2-level exclusive scan ----------------

__global__ void scan_block_k(const int* __restrict__ in, int* __restrict__ out,
                             int* __restrict__ partials, int n) {
    __shared__ int tmp[256];
    int i = blockIdx.x * 256 + threadIdx.x;
    int v = (i < n) ? in[i] : 0;
    tmp[threadIdx.x] = v;
    __syncthreads();
    for (int off = 1; off < 256; off <<= 1) {
        int t = (threadIdx.x >= off) ? tmp[threadIdx.x - off] : 0;
        __syncthreads();
        tmp[threadIdx.x] += t;
        __syncthreads();
    }
    if (i < n) out[i] = tmp[threadIdx.x] - v;
    if (threadIdx.x == 255) partials[blockIdx.x] = tmp[255];
}

__global__ void scan_partials_k(int* __restrict__ partials, int nb) {
    __shared__ int tmp[256];
    int v = (threadIdx.x < nb) ? partials[threadIdx.x] : 0;
    tmp[threadIdx.x] = v;
    __syncthreads();
    for (int off = 1; off < 256; off <<= 1) {
        int t = (threadIdx.x >= off) ? tmp[threadIdx.x - off] : 0;
        __syncthreads();
        tmp[threadIdx.x] += t;
        __syncthreads();
    }
    if (threadIdx.x < nb) partials[threadIdx.x] = tmp[threadIdx.x] - v;
}

// ---------------- FUSED: scatter2 (blocks 0..NBK) ∥ gemm1 unscaled blocked (blocks NBK..) ----------------
// gemm1: h1 fp16 UNSCALED, feature-blocked [4][n][32]; slice = wave>>2.

__global__ __launch_bounds__(1024) void fused_scatter_gemm1_k(
        const int* __restrict__ src, const int* __restrict__ dst,
        const int* __restrict__ goff, const int* __restrict__ partial2,
        unsigned* __restrict__ tmp, int ne, int n_buckets,
        const float* __restrict__ in, const _Float16* __restrict__ Wt,
        __half* __restrict__ hout, int n_rows) {
    __shared__ int cur[MAXBUCKET];
    __shared__ _Float16 xs[64][136];
    const int t = threadIdx.x;

    if (blockIdx.x < NBK) {
        for (int b = t; b < n_buckets; b += 1024)
            cur[b] = goff[(size_t)b * NBK + blockIdx.x] + partial2[b];
        __syncthreads();
        const int chunk = (ne + NBK - 1) / NBK;
        const int beg = blockIdx.x * chunk;
        const int end = min(ne, beg + chunk);
        for (int e = beg + t; e < end; e += 1024) {
            int d = dst[e];
            int s = src[e];
            int pos = atomicAdd(&cur[d / NPB], 1);
            tmp[pos] = ((unsigned)(d & (NPB - 1)) << SRC_BITS) | (unsigned)s;
        }
        return;
    }

    const int row0 = (blockIdx.x - NBK) * 64;

    #pragma unroll
    for (int i = 0; i < 2; ++i) {
        int q = t + i * 1024;
        int row = q >> 5, c4 = (q & 31) * 4;
        float4 v = make_float4(0.f, 0.f, 0.f, 0.f);
        if (row0 + row < n_rows) v = *(const float4*)(in + (size_t)(row0 + row) * 128 + c4);
        U2H4 cv;
        cv.h[0] = (_Float16)v.x; cv.h[1] = (_Float16)v.y;
        cv.h[2] = (_Float16)v.z; cv.h[3] = (_Float16)v.w;
        *(uint2*)&xs[row][c4] = cv.u;
    }
    __syncthreads();

    const int lane = t & 63;
    const int wave = t >> 6;            // 0..15
    const int r0 = (wave & 3) * 16;     // row tile
    const int slice = wave >> 2;        // feature slice 0..3 (32 cols each)
    const int lrow = lane & 15;
    const int kgrp = (lane >> 4) * 8;

    f32x4 acc[2];
    acc[0] = (f32x4){0.f, 0.f, 0.f, 0.f};
    acc[1] = (f32x4){0.f, 0.f, 0.f, 0.f};

    #pragma unroll
    for (int kk = 0; kk < 4; ++kk) {
        const int k0 = kk * 32 + kgrp;
        half8 a = *(const half8*)&xs[r0 + lrow][k0];
        #pragma unroll
        for (int ct = 0; ct < 2; ++ct) {
            half8 b = *(const half8*)(Wt + (size_t)(slice * 32 + ct * 16 + lrow) * 128 + k0);
            acc[ct] = __builtin_amdgcn_mfma_f32_16x16x32_f16(a, b, acc[ct], 0, 0, 0);
        }
    }

    #pragma unroll
    for (int i = 0; i < 4; ++i) {
        int row = row0 + r0 + (lane >> 4) * 4 + i;
        if (row < n_rows) {
            __half* p = hout + ((size_t)slice * n_rows + row) * 32 + lrow;
            p[0]  = __float2half(acc[0][i]);
            p[16] = __float2half(acc[1][i]);
        }
    }
}

// ---------------- pass 3: per-bucket deg/dis/rowoff + final CSR placement ----------------

__global__ __launch_bounds__(NPB) void binC_k(const unsigned* __restrict__ tmp,
                                              const int* __restrict__ goff,
                                              const int* __restrict__ partial2,
                                              int* __restrict__ deg, float* __restrict__ dis,
                                              int* __restrict__ rowoff, int* __restrict__ csr,
                                              int n_nodes, int ne, int n_buckets) {
    __shared__ int cnt[NPB];
    __shared__ int sc[NPB];
    const int t = threadIdx.x;
    const int bid = blockIdx.x;
    const int base = goff[(size_t)bid * NBK] + partial2[bid];
    const int end = (bid + 1 < n_buckets) ? goff[(size_t)(bid + 1) * NBK] + partial2[bid + 1] : ne;

    cnt[t] = 0;
    __syncthreads();
    for (int j = base + t; j < end; j += NPB)
        atomicAdd(&cnt[tmp[j] >> SRC_BITS], 1);
    __syncthreads();

    int mydeg = cnt[t];
    sc[t] = mydeg;
    __syncthreads();
    for (int off = 1; off < NPB; off <<= 1) {
        int v = (t >= off) ? sc[t - off] : 0;
        __syncthreads();
        sc[t] += v;
        __syncthreads();
    }
    int excl = sc[t] - mydeg;
    int node = bid * NPB + t;
    if (node < n_nodes) {
        deg[node] = mydeg;
        dis[node] = rsqrtf((float)(mydeg + 1));
        rowoff[node] = base + excl;
    }
    cnt[t] = base + excl;
    __syncthreads();
    for (int j = base + t; j < end; j += NPB) {
        unsigned e = tmp[j];
        int ld = e >> SRC_BITS;
        int s  = e & ((1u << SRC_BITS) - 1);
        int pos = atomicAdd(&cnt[ld], 1);
        csr[pos] = s;
    }
}

// ---------------- pull1: XCD-pinned 4-slice blocked, cached loads ----------------
// h1 blocked [4][n][32] fp16, unscaled. r=bid&7 -> XCD; slice=r>>1; chunk=(bid>>3)*2+(r&1).
// 4 lanes/node x 8 feats. agg1relu also blocked [4][n][32] fp16.

__global__ void pull1_k(const __half* __restrict__ g, const int* __restrict__ rowoff,
                        const int* __restrict__ deg, const int* __restrict__ csr,
                        const float* __restrict__ dis, const float* __restrict__ b,
                        __half* __restrict__ out, int n_nodes) {
    const int bid = blockIdx.x;
    const int r = bid & 7;
    const int slice = r >> 1;
    const int chunk = (bid >> 3) * 2 + (r & 1);
    const int node = chunk * 64 + (threadIdx.x >> 2);
    if (node >= n_nodes) return;
    const int fl = (threadIdx.x & 3) * 8;          // feature within slice
    const __half* gs = g + (size_t)slice * n_nodes * 32;
    int beg = rowoff[node];
    int end = beg + deg[node];
    float dd = dis[node];

    float acc[8];
    {
        F4H8 v; v.f = *(const float4*)(gs + (size_t)node * 32 + fl);
        #pragma unroll
        for (int k = 0; k < 4; ++k) {
            float2 p = __half22float2(v.h[k]);
            acc[2 * k] = dd * p.x; acc[2 * k + 1] = dd * p.y;
        }
    }

    int j = beg;
    for (; j + 2 <= end; j += 2) {
        int s0 = csr[j];
        int s1 = csr[j + 1];
        float w0 = dis[s0];
        float w1 = dis[s1];
        F4H8 v0; v0.f = *(const float4*)(gs + (size_t)s0 * 32 + fl);
        F4H8 v1; v1.f = *(const float4*)(gs + (size_t)s1 * 32 + fl);
        #pragma unroll
        for (int k = 0; k < 4; ++k) {
            float2 p0 = __half22float2(v0.h[k]);
            float2 p1 = __half22float2(v1.h[k]);
            acc[2 * k]     += w0 * p0.x + w1 * p1.x;
            acc[2 * k + 1] += w0 * p0.y + w1 * p1.y;
        }
    }
    if (j < end) {
        int s = csr[j];
        float w = dis[s];
        F4H8 v; v.f = *(const float4*)(gs + (size_t)s * 32 + fl);
        #pragma unroll
        for (int k = 0; k < 4; ++k) {
            float2 p = __half22float2(v.h[k]);
            acc[2 * k] += w * p.x; acc[2 * k + 1] += w * p.y;
        }
    }

    const int f0 = slice * 32 + fl;                // global feature (for bias)
    float4 b0 = *(const float4*)(b + f0);
    float4 b1 = *(const float4*)(b + f0 + 4);
    F4H8 o;
    o.h[0] = __floats2half2_rn(fmaxf(b0.x + dd * acc[0], 0.f), fmaxf(b0.y + dd * acc[1], 0.f));
    o.h[1] = __floats2half2_rn(fmaxf(b0.z + dd * acc[2], 0.f), fmaxf(b0.w + dd * acc[3], 0.f));
    o.h[2] = __floats2half2_rn(fmaxf(b1.x + dd * acc[4], 0.f), fmaxf(b1.y + dd * acc[5], 0.f));
    o.h[3] = __floats2half2_rn(fmaxf(b1.z + dd * acc[6], 0.f), fmaxf(b1.w + dd * acc[7], 0.f));
    *(float4*)(out + ((size_t)slice * n_nodes + node) * 32 + fl) = o.f;
}

// ---------------- GEMM2: g2[n][32] (fp16) = dis[n] * (agg1relu_blocked @ W[128][32]) ----------------

__global__ __launch_bounds__(256) void gemm2_k(const __half* __restrict__ in,
                                               const float* __restrict__ W,
                                               const float* __restrict__ dis,
                                               __half* __restrict__ out, int n_rows) {
    __shared__ float xs[64][132];
    __shared__ float wt[128][32];
    const int t = threadIdx.x;
    const int row0 = blockIdx.x * 64;

    // stage blocked fp16 input: q -> slice (q>>8), row ((q>>2)&63), f8 ((q&3)*8)
    #pragma unroll
    for (int i = 0; i < 4; ++i) {
        int q = t + i * 256;
        int slice = q >> 8, row = (q >> 2) & 63, f8 = (q & 3) * 8;
        F4H8 v;
        v.f = make_float4(0.f, 0.f, 0.f, 0.f);
        if (row0 + row < n_rows)
            v.f = *(const float4*)(in + ((size_t)slice * n_rows + row0 + row) * 32 + f8);
        #pragma unroll
        for (int k = 0; k < 4; ++k) {
            float2 p = __half22float2(v.h[k]);
            xs[row][slice * 32 + f8 + 2 * k] = p.x;
            xs[row][slice * 32 + f8 + 2 * k + 1] = p.y;
        }
    }
    #pragma unroll
    for (int i = 0; i < 4; ++i) {
        int q = t + i * 256;
        int kk = q >> 3, c4 = (q & 7) * 4;
        *(float4*)&wt[kk][c4] = *(const float4*)(W + (size_t)kk * 32 + c4);
    }
    __syncthreads();

    const int c4 = (t & 7) * 4;
    const int r2 = (t >> 3) * 2;

    float acc[2][4];
    #pragma unroll
    for (int i = 0; i < 2; ++i)
        #pragma unroll
        for (int j = 0; j < 4; ++j) acc[i][j] = 0.f;

    #pragma unroll 4
    for (int k = 0; k < 128; ++k) {
        float x0 = xs[r2][k], x1 = xs[r2 + 1][k];
        float4 w = *(float4*)&wt[k][c4];
        acc[0][0] += x0 * w.x; acc[0][1] += x0 * w.y; acc[0][2] += x0 * w.z; acc[0][3] += x0 * w.w;
        acc[1][0] += x1 * w.x; acc[1][1] += x1 * w.y; acc[1][2] += x1 * w.z; acc[1][3] += x1 * w.w;
    }

    #pragma unroll
    for (int i = 0; i < 2; ++i) {
        int row = row0 + r2 + i;
        if (row < n_rows) {
            float sc = dis[row];
            U2H4 cv;
            cv.h[0] = (_Float16)(sc * acc[i][0]);
            cv.h[1] = (_Float16)(sc * acc[i][1]);
            cv.h[2] = (_Float16)(sc * acc[i][2]);
            cv.h[3] = (_Float16)(sc * acc[i][3]);
            *(uint2*)(out + (size_t)row * 32 + c4) = cv.u;
        }
    }
}

// ---------------- pull2 (fp16 g2, 3.2MB total working set): 8 lanes/node ----------------

__global__ void pull2_k(const __half* __restrict__ g, const int* __restrict__ rowoff,
                        const int* __restrict__ deg, const int* __restrict__ csr,
                        const float* __restrict__ dis, const float* __restrict__ b,
                        float* __restrict__ out, int n_nodes) {
    int gt = blockIdx.x * blockDim.x + threadIdx.x;
    int node = gt >> 3;
    int f0 = (gt & 7) * 4;
    if (node >= n_nodes) return;
    int beg = rowoff[node];
    int end = beg + deg[node];
    float dd = dis[node];

    float acc[4];
    {
        U2H4 v; v.u = *(const uint2*)(g + (size_t)node * 32 + f0);
        #pragma unroll
        for (int k = 0; k < 4; ++k) acc[k] = (float)v.h[k];
    }

    int j = beg;
    for (; j + 2 <= end; j += 2) {
        int s0 = csr[j];
        int s1 = csr[j + 1];
        U2H4 v0; v0.u = *(const uint2*)(g + (size_t)s0 * 32 + f0);
        U2H4 v1; v1.u = *(const uint2*)(g + (size_t)s1 * 32 + f0);
        #pragma unroll
        for (int k = 0; k < 4; ++k) acc[k] += (float)v0.h[k] + (float)v1.h[k];
    }
    if (j < end) {
        int s = csr[j];
        U2H4 v; v.u = *(const uint2*)(g + (size_t)s * 32 + f0);
        #pragma unroll
        for (int k = 0; k < 4; ++k) acc[k] += (float)v.h[k];
    }

    float4 bb = *(const float4*)(b + f0);
    *(float4*)(out + (size_t)node * 32 + f0) =
        make_float4(bb.x + dd * acc[0], bb.y + dd * acc[1],
                    bb.z + dd * acc[2], bb.w + dd * acc[3]);
}

// ---------------- GEMM3: g3[n][32] = dis[n] * (relu(in[n][32]) @ W[32][32]) ----------------

__global__ __launch_bounds__(256) void gemm3_k(const float* __restrict__ in,
                                               const float* __restrict__ W,
                                               const float* __restrict__ dis,
                                               float* __restrict__ out, int n_rows) {
    __shared__ float xs[64][36];
    __shared__ float wt[32][32];
    const int t = threadIdx.x;
    const int row0 = blockIdx.x * 64;

    #pragma unroll
    for (int i = 0; i < 2; ++i) {
        int q = t + i * 256;
        int row = q >> 3, c4 = (q & 7) * 4;
        float4 v = make_float4(0.f, 0.f, 0.f, 0.f);
        if (row0 + row < n_rows) {
            v = *(const float4*)(in + (size_t)(row0 + row) * 32 + c4);
            v.x = fmaxf(v.x, 0.f); v.y = fmaxf(v.y, 0.f);
            v.z = fmaxf(v.z, 0.f); v.w = fmaxf(v.w, 0.f);
        }
        *(float4*)&xs[row][c4] = v;
    }
    {
        int kk = t >> 3, c4 = (t & 7) * 4;
        *(float4*)&wt[kk][c4] = *(const float4*)(W + (size_t)kk * 32 + c4);
    }
    __syncthreads();

    const int c4 = (t & 7) * 4;
    const int r2 = (t >> 3) * 2;

    float acc[2][4];
    #pragma unroll
    for (int i = 0; i < 2; ++i)
        #pragma unroll
        for (int j = 0; j < 4; ++j) acc[i][j] = 0.f;

    #pragma unroll
    for (int k = 0; k < 32; ++k) {
        float x0 = xs[r2][k], x1 = xs[r2 + 1][k];
        float4 w = *(float4*)&wt[k][c4];
        acc[0][0] += x0 * w.x; acc[0][1] += x0 * w.y; acc[0][2] += x0 * w.z; acc[0][3] += x0 * w.w;
        acc[1][0] += x1 * w.x; acc[1][1] += x1 * w.y; acc[1][2] += x1 * w.z; acc[1][3] += x1 * w.w;
    }

    #pragma unroll
    for (int i = 0; i < 2; ++i) {
        int row = row0 + r2 + i;
        if (row < n_rows) {
            float sc = dis[row];
            *(float4*)(out + (size_t)row * 32 + c4) =
                make_float4(sc * acc[i][0], sc * acc[i][1], sc * acc[i][2], sc * acc[i][3]);
        }
    }
}

// ---------------- fused pull3 + head (sel nodes only): 8 lanes/sel-entry ----------------

__global__ void pull_head_k(const float* __restrict__ g, const int* __restrict__ rowoff,
                            const int* __restrict__ deg, const int* __restrict__ csr,
                            const float* __restrict__ dis, const float* __restrict__ b3,
                            const int* __restrict__ sel, const float* __restrict__ Wl,
                            const float* __restrict__ bl, float* __restrict__ out, int n_sel) {
    int gt = blockIdx.x * blockDim.x + threadIdx.x;
    int t = gt >> 3;
    int f0 = (gt & 7) * 4;
    if (t >= n_sel) return;
    int node = sel[t];
    int beg = rowoff[node];
    int end = beg + deg[node];
    float dd = dis[node];

    float4 acc = *(const float4*)(g + (size_t)node * 32 + f0);

    int j = beg;
    for (; j + 2 <= end; j += 2) {
        int s0 = csr[j];
        int s1 = csr[j + 1];
        float4 h0 = *(const float4*)(g + (size_t)s0 * 32 + f0);
        float4 h1 = *(const float4*)(g + (size_t)s1 * 32 + f0);
        acc.x += h0.x + h1.x;
        acc.y += h0.y + h1.y;
        acc.z += h0.z + h1.z;
        acc.w += h0.w + h1.w;
    }
    if (j < end) {
        int s = csr[j];
        float4 hs = *(const float4*)(g + (size_t)s * 32 + f0);
        acc.x += hs.x; acc.y += hs.y; acc.z += hs.z; acc.w += hs.w;
    }

    float4 bb = *(const float4*)(b3 + f0);
    float a0 = bb.x + dd * acc.x;
    float a1 = bb.y + dd * acc.y;
    float a2 = bb.z + dd * acc.z;
    float a3 = bb.w + dd * acc.w;

    float l0 = a0 * Wl[(f0 + 0) * 2] + a1 * Wl[(f0 + 1) * 2]
             + a2 * Wl[(f0 + 2) * 2] + a3 * Wl[(f0 + 3) * 2];
    float l1 = a0 * Wl[(f0 + 0) * 2 + 1] + a1 * Wl[(f0 + 1) * 2 + 1]
             + a2 * Wl[(f0 + 2) * 2 + 1] + a3 * Wl[(f0 + 3) * 2 + 1];
    #pragma unroll
    for (int m = 1; m < 8; m <<= 1) {
        l0 += __shfl_xor(l0, m);
        l1 += __shfl_xor(l1, m);
    }
    if ((gt & 7) == 0) {
        l0 += bl[0]; l1 += bl[1];
        float mx = fmaxf(l0, l1);
        float e0 = expf(l0 - mx), e1 = expf(l1 - mx);
        float s = e0 + e1;
        float ls = logf(s);
        *(float2*)(out + (size_t)t * 2) = make_float2((l0 - mx) - ls, (l1 - mx) - ls);
        *(float2*)(out + 2 * (size_t)n_sel + (size_t)t * 2) = make_float2(e0 / s, e1 / s);
    }
}

// ---------------- launch ----------------

extern "C" void kernel_launch(void* const* d_in, const int* in_sizes, int n_in,
                              void* d_out, int out_size, void* d_ws, size_t ws_size,
                              hipStream_t stream) {
    const float* x  = (const float*)d_in[0];
    const int* edge = (const int*)d_in[1];
    const int* sel  = (const int*)d_in[2];
    const float* W1 = (const float*)d_in[4];
    const float* b1 = (const float*)d_in[5];
    const float* W2 = (const float*)d_in[6];
    const float* b2 = (const float*)d_in[7];
    const float* W3 = (const float*)d_in[8];
    const float* b3 = (const float*)d_in[9];
    const float* Wl = (const float*)d_in[10];
    const float* bl = (const float*)d_in[11];
    float* out = (float*)d_out;

    const int n_nodes = in_sizes[0] / F_IN;
    const int n_edges = in_sizes[1] / 2;
    const int n_sel   = in_sizes[2];
    const int* srcv = edge;
    const int* dstv = edge + n_edges;
    const int n_buckets = (n_nodes + NPB - 1) / NPB;   // 196
    const int n_gh = n_buckets * NBK;                  // 50176

    char* ws = (char*)d_ws;
    int*       deg      = (int*)ws;       ws += alignup((size_t)n_nodes * 4);
    float*     dis      = (float*)ws;     ws += alignup((size_t)n_nodes * 4);
    int*       rowoff   = (int*)ws;       ws += alignup((size_t)n_nodes * 4);
    int*       ghist    = (int*)ws;       ws += alignup((size_t)n_gh * 4);
    int*       goff     = (int*)ws;       ws += alignup((size_t)n_gh * 4);
    int*       partial2 = (int*)ws;       ws += alignup(1024);
    _Float16*  Wt       = (_Float16*)ws;  ws += alignup(128 * 128 * 2);
    unsigned*  tmp      = (unsigned*)ws;  ws += alignup((size_t)n_edges * 4);
    int*       csr      = (int*)ws;       ws += alignup((size_t)n_edges * 4);
    char*      bufA     = ws;             ws += alignup((size_t)n_nodes * HID * 4);
    char*      bufB     = ws;

    const int B = 256;
    #define GRD(n) (((n) + B - 1) / B)
    const int nblk2 = GRD(n_gh);   // 196
    const int gemm_blocks = (n_nodes + 63) / 64;   // 782
    const int chunks = gemm_blocks;                // node-chunks of 64

    // CSR build prefix
    hist_k<<<NBK, 1024, 0, stream>>>(dstv, ghist, W1, Wt, n_edges, n_buckets);
    scan_block_k<<<nblk2, B, 0, stream>>>(ghist, goff, partial2, n_gh);
    scan_partials_k<<<1, B, 0, stream>>>(partial2, nblk2);

    // fused: edge partition ∥ gemm1 (unscaled fp16, feature-blocked [4][n][32])
    fused_scatter_gemm1_k<<<NBK + gemm_blocks, 1024, 0, stream>>>(
        srcv, dstv, goff, partial2, tmp, n_edges, n_buckets,
        x, Wt, (__half*)bufA, n_nodes);

    // finalize CSR
    binC_k<<<n_buckets, NPB, 0, stream>>>(tmp, goff, partial2, deg, dis, rowoff, csr,
                                          n_nodes, n_edges, n_buckets);

    // layer 1 aggregate: XCD-pinned 4-slice blocked pull; agg1relu blocked fp16
    {
        int g1 = 8 * ((chunks + 1) / 2);           // 3128
        pull1_k<<<g1, B, 0, stream>>>((const __half*)bufA, rowoff, deg, csr,
                                      dis, b1, (__half*)bufB, n_nodes);
    }

    // layer 2: g2 fp16 = dis*(agg1relu@W2); agg2 fp32
    gemm2_k<<<gemm_blocks, B, 0, stream>>>((const __half*)bufB, W2, dis, (__half*)bufA, n_nodes);
    pull2_k<<<GRD(n_nodes * 8), B, 0, stream>>>((const __half*)bufA, rowoff, deg, csr,
                                                dis, b2, (float*)bufB, n_nodes);

    // layer 3: g3 fp32; pull+head on selected nodes only
    gemm3_k<<<gemm_blocks, B, 0, stream>>>((const float*)bufB, W3, dis, (float*)bufA, n_nodes);
    pull_head_k<<<GRD(n_sel * 8), B, 0, stream>>>((const float*)bufA, rowoff, deg, csr, dis, b3,
                                                  sel, Wl, bl, out, n_sel);

    #undef GRD
}

// Round 18
// 129.571 us; speedup vs baseline: 1.1002x; 1.1002x over previous
//
#include <hip/hip_runtime.h>
#include <hip/hip_fp16.h>

#define F_IN 128
#define HID 128
#define HID4 32
#define NPB 256          // nodes per CSR bucket
#define SRC_BITS 17      // n_nodes = 50000 < 2^17
#define NBK 256          // partition chunks/blocks (== 256 so partial idx == bucket idx)
#define MAXBUCKET 256    // LDS counter array size (n_buckets = 196)

static inline size_t alignup(size_t x) { return (x + 255) & ~(size_t)255; }

typedef _Float16 half8 __attribute__((ext_vector_type(8)));
typedef float f32x4 __attribute__((ext_vector_type(4)));

union F4H8 { float4 f; __half2 h[4]; };   // 8 halfs = 16 B
union U2H4 { uint2 u; _Float16 h[4]; };   // 4 halfs = 8 B

// ---------------- pass 1: bucket histogram (+ folded W1 transpose to fp16) ----------------

__global__ __launch_bounds__(1024) void hist_k(const int* __restrict__ dst,
                                               int* __restrict__ ghist,
                                               const float* __restrict__ W1,
                                               _Float16* __restrict__ Wt,
                                               int ne, int n_buckets) {
    __shared__ int h[MAXBUCKET];
    const int t = threadIdx.x;
    if (blockIdx.x < 16) {
        int q = blockIdx.x * 1024 + t;
        int k = q >> 7, n = q & 127;
        Wt[n * 128 + k] = (_Float16)W1[q];
    }
    for (int b = t; b < n_buckets; b += 1024) h[b] = 0;
    __syncthreads();
    const int chunk = (ne + NBK - 1) / NBK;
    const int beg = blockIdx.x * chunk;
    const int end = min(ne, beg + chunk);
    for (int e = beg + t; e < end; e += 1024)
        atomicAdd(&h[dst[e] / NPB], 1);
    __syncthreads();
    for (int b = t; b < n_buckets; b += 1024)
        ghist[(size_t)b * NBK + blockIdx.x] = h[b];
}

// ---------------- 2-level exclusive scan ----------------

__global__ void scan_block_k(const int* __restrict__ in, int* __restrict__ out,
                             int* __restrict__ partials, int n) {
    __shared__ int tmp[256];
    int i = blockIdx.x * 256 + threadIdx.x;
    int v = (i < n) ? in[i] : 0;
    tmp[threadIdx.x] = v;
    __syncthreads();
    for (int off = 1; off < 256; off <<= 1) {
        int t = (threadIdx.x >= off) ? tmp[threadIdx.x - off] : 0;
        __syncthreads();
        tmp[threadIdx.x] += t;
        __syncthreads();
    }
    if (i < n) out[i] = tmp[threadIdx.x] - v;
    if (threadIdx.x == 255) partials[blockIdx.x] = tmp[255];
}

__global__ void scan_partials_k(int* __restrict__ partials, int nb) {
    __shared__ int tmp[256];
    int v = (threadIdx.x < nb) ? partials[threadIdx.x] : 0;
    tmp[threadIdx.x] = v;
    __syncthreads();
    for (int off = 1; off < 256; off <<= 1) {
        int t = (threadIdx.x >= off) ? tmp[threadIdx.x - off] : 0;
        __syncthreads();
        tmp[threadIdx.x] += t;
        __syncthreads();
    }
    if (threadIdx.x < nb) partials[threadIdx.x] = tmp[threadIdx.x] - v;
}

// ---------------- FUSED: scatter2 (blocks 0..NBK) ∥ gemm1 unscaled (blocks NBK..) ----------------
// gemm1 no longer needs dis (h1 unscaled) -> independent of the CSR chain past scan.
// 1024 threads. gemm1: 64 rows/block, 16 waves; wave w: rows (w&3)*16.., cols (w>>2)*32 + {0,16}.

__global__ __launch_bounds__(1024) void fused_scatter_gemm1_k(
        const int* __restrict__ src, const int* __restrict__ dst,
        const int* __restrict__ goff, const int* __restrict__ partial2,
        unsigned* __restrict__ tmp, int ne, int n_buckets,
        const float* __restrict__ in, const _Float16* __restrict__ Wt,
        __half* __restrict__ hout, int n_rows) {
    __shared__ int cur[MAXBUCKET];
    __shared__ _Float16 xs[64][136];
    const int t = threadIdx.x;

    if (blockIdx.x < NBK) {
        // ---- scatter2 branch ----
        for (int b = t; b < n_buckets; b += 1024)
            cur[b] = goff[(size_t)b * NBK + blockIdx.x] + partial2[b];
        __syncthreads();
        const int chunk = (ne + NBK - 1) / NBK;
        const int beg = blockIdx.x * chunk;
        const int end = min(ne, beg + chunk);
        for (int e = beg + t; e < end; e += 1024) {
            int d = dst[e];
            int s = src[e];
            int pos = atomicAdd(&cur[d / NPB], 1);
            tmp[pos] = ((unsigned)(d & (NPB - 1)) << SRC_BITS) | (unsigned)s;
        }
        return;
    }

    // ---- gemm1 branch: h1[n][128] (fp16, UNSCALED) = x[n][128] @ W1 ----
    const int row0 = (blockIdx.x - NBK) * 64;

    #pragma unroll
    for (int i = 0; i < 2; ++i) {
        int q = t + i * 1024;
        int row = q >> 5, c4 = (q & 31) * 4;
        float4 v = make_float4(0.f, 0.f, 0.f, 0.f);
        if (row0 + row < n_rows) v = *(const float4*)(in + (size_t)(row0 + row) * 128 + c4);
        U2H4 cv;
        cv.h[0] = (_Float16)v.x; cv.h[1] = (_Float16)v.y;
        cv.h[2] = (_Float16)v.z; cv.h[3] = (_Float16)v.w;
        *(uint2*)&xs[row][c4] = cv.u;
    }
    __syncthreads();

    const int lane = t & 63;
    const int wave = t >> 6;            // 0..15
    const int r0 = (wave & 3) * 16;     // row tile
    const int cg = (wave >> 2) * 32;    // col group (32 cols)
    const int lrow = lane & 15;
    const int kgrp = (lane >> 4) * 8;

    f32x4 acc[2];
    acc[0] = (f32x4){0.f, 0.f, 0.f, 0.f};
    acc[1] = (f32x4){0.f, 0.f, 0.f, 0.f};

    #pragma unroll
    for (int kk = 0; kk < 4; ++kk) {
        const int k0 = kk * 32 + kgrp;
        half8 a = *(const half8*)&xs[r0 + lrow][k0];
        #pragma unroll
        for (int ct = 0; ct < 2; ++ct) {
            half8 b = *(const half8*)(Wt + (size_t)(cg + ct * 16 + lrow) * 128 + k0);
            acc[ct] = __builtin_amdgcn_mfma_f32_16x16x32_f16(a, b, acc[ct], 0, 0, 0);
        }
    }

    #pragma unroll
    for (int i = 0; i < 4; ++i) {
        int row = row0 + r0 + (lane >> 4) * 4 + i;
        if (row < n_rows) {
            __half* p = hout + (size_t)row * 128 + cg + lrow;
            p[0]  = __float2half(acc[0][i]);
            p[16] = __float2half(acc[1][i]);
        }
    }
}

// ---------------- pass 3: per-bucket deg/dis/rowoff + final CSR placement ----------------

__global__ __launch_bounds__(NPB) void binC_k(const unsigned* __restrict__ tmp,
                                              const int* __restrict__ goff,
                                              const int* __restrict__ partial2,
                                              int* __restrict__ deg, float* __restrict__ dis,
                                              int* __restrict__ rowoff, int* __restrict__ csr,
                                              int n_nodes, int ne, int n_buckets) {
    __shared__ int cnt[NPB];
    __shared__ int sc[NPB];
    const int t = threadIdx.x;
    const int bid = blockIdx.x;
    const int base = goff[(size_t)bid * NBK] + partial2[bid];
    const int end = (bid + 1 < n_buckets) ? goff[(size_t)(bid + 1) * NBK] + partial2[bid + 1] : ne;

    cnt[t] = 0;
    __syncthreads();
    for (int j = base + t; j < end; j += NPB)
        atomicAdd(&cnt[tmp[j] >> SRC_BITS], 1);
    __syncthreads();

    int mydeg = cnt[t];
    sc[t] = mydeg;
    __syncthreads();
    for (int off = 1; off < NPB; off <<= 1) {
        int v = (t >= off) ? sc[t - off] : 0;
        __syncthreads();
        sc[t] += v;
        __syncthreads();
    }
    int excl = sc[t] - mydeg;
    int node = bid * NPB + t;
    if (node < n_nodes) {
        deg[node] = mydeg;
        dis[node] = rsqrtf((float)(mydeg + 1));
        rowoff[node] = base + excl;
    }
    cnt[t] = base + excl;
    __syncthreads();
    for (int j = base + t; j < end; j += NPB) {
        unsigned e = tmp[j];
        int ld = e >> SRC_BITS;
        int s  = e & ((1u << SRC_BITS) - 1);
        int pos = atomicAdd(&cnt[ld], 1);
        csr[pos] = s;
    }
}

// ---------------- pull1: 16 lanes/node; h1 unscaled -> gathers dis[s]; emits fp16 relu(agg1) ----------------
// agg1[d][:] = relu( b1 + dis[d]*( dis[d]*h1[d][:] + sum_e dis[s]*h1[s][:] ) )

__global__ void pull1_k(const __half* __restrict__ g, const int* __restrict__ rowoff,
                        const int* __restrict__ deg, const int* __restrict__ csr,
                        const float* __restrict__ dis, const float* __restrict__ b,
                        __half* __restrict__ out, int n_nodes) {
    int gt = blockIdx.x * blockDim.x + threadIdx.x;
    int node = gt >> 4;
    int f0 = (gt & 15) * 8;
    if (node >= n_nodes) return;
    int beg = rowoff[node];
    int end = beg + deg[node];
    float dd = dis[node];

    float acc[8];
    {
        F4H8 v; v.f = *(const float4*)(g + (size_t)node * 128 + f0);
        #pragma unroll
        for (int k = 0; k < 4; ++k) {
            float2 p = __half22float2(v.h[k]);
            acc[2 * k] = dd * p.x; acc[2 * k + 1] = dd * p.y;
        }
    }

    int j = beg;
    for (; j + 2 <= end; j += 2) {
        int s0 = csr[j];
        int s1 = csr[j + 1];
        float w0 = dis[s0];
        float w1 = dis[s1];
        F4H8 v0; v0.f = *(const float4*)(g + (size_t)s0 * 128 + f0);
        F4H8 v1; v1.f = *(const float4*)(g + (size_t)s1 * 128 + f0);
        #pragma unroll
        for (int k = 0; k < 4; ++k) {
            float2 p0 = __half22float2(v0.h[k]);
            float2 p1 = __half22float2(v1.h[k]);
            acc[2 * k]     += w0 * p0.x + w1 * p1.x;
            acc[2 * k + 1] += w0 * p0.y + w1 * p1.y;
        }
    }
    if (j < end) {
        int s = csr[j];
        float w = dis[s];
        F4H8 v; v.f = *(const float4*)(g + (size_t)s * 128 + f0);
        #pragma unroll
        for (int k = 0; k < 4; ++k) {
            float2 p = __half22float2(v.h[k]);
            acc[2 * k] += w * p.x; acc[2 * k + 1] += w * p.y;
        }
    }

    float4 b0 = *(const float4*)(b + f0);
    float4 b1 = *(const float4*)(b + f0 + 4);
    F4H8 o;
    o.h[0] = __floats2half2_rn(fmaxf(b0.x + dd * acc[0], 0.f), fmaxf(b0.y + dd * acc[1], 0.f));
    o.h[1] = __floats2half2_rn(fmaxf(b0.z + dd * acc[2], 0.f), fmaxf(b0.w + dd * acc[3], 0.f));
    o.h[2] = __floats2half2_rn(fmaxf(b1.x + dd * acc[4], 0.f), fmaxf(b1.y + dd * acc[5], 0.f));
    o.h[3] = __floats2half2_rn(fmaxf(b1.z + dd * acc[6], 0.f), fmaxf(b1.w + dd * acc[7], 0.f));
    *(float4*)(out + (size_t)node * 128 + f0) = o.f;
}

// ---------------- GEMM2: g2[n][32] (fp16) = dis[n] * (agg1relu[n][128] @ W[128][32]) ----------------

__global__ __launch_bounds__(256) void gemm2_k(const __half* __restrict__ in,
                                               const float* __restrict__ W,
                                               const float* __restrict__ dis,
                                               __half* __restrict__ out, int n_rows) {
    __shared__ float xs[64][132];
    __shared__ float wt[128][32];
    const int t = threadIdx.x;
    const int row0 = blockIdx.x * 64;

    #pragma unroll
    for (int i = 0; i < 4; ++i) {
        int q = t + i * 256;
        int row = q >> 4, c8 = (q & 15) * 8;
        F4H8 v;
        v.f = make_float4(0.f, 0.f, 0.f, 0.f);
        if (row0 + row < n_rows)
            v.f = *(const float4*)(in + (size_t)(row0 + row) * 128 + c8);
        #pragma unroll
        for (int k = 0; k < 4; ++k) {
            float2 p = __half22float2(v.h[k]);
            xs[row][c8 + 2 * k] = p.x;
            xs[row][c8 + 2 * k + 1] = p.y;
        }
    }
    #pragma unroll
    for (int i = 0; i < 4; ++i) {
        int q = t + i * 256;
        int kk = q >> 3, c4 = (q & 7) * 4;
        *(float4*)&wt[kk][c4] = *(const float4*)(W + (size_t)kk * 32 + c4);
    }
    __syncthreads();

    const int c4 = (t & 7) * 4;
    const int r2 = (t >> 3) * 2;

    float acc[2][4];
    #pragma unroll
    for (int i = 0; i < 2; ++i)
        #pragma unroll
        for (int j = 0; j < 4; ++j) acc[i][j] = 0.f;

    #pragma unroll 4
    for (int k = 0; k < 128; ++k) {
        float x0 = xs[r2][k], x1 = xs[r2 + 1][k];
        float4 w = *(float4*)&wt[k][c4];
        acc[0][0] += x0 * w.x; acc[0][1] += x0 * w.y; acc[0][2] += x0 * w.z; acc[0][3] += x0 * w.w;
        acc[1][0] += x1 * w.x; acc[1][1] += x1 * w.y; acc[1][2] += x1 * w.z; acc[1][3] += x1 * w.w;
    }

    #pragma unroll
    for (int i = 0; i < 2; ++i) {
        int row = row0 + r2 + i;
        if (row < n_rows) {
            float sc = dis[row];
            U2H4 cv;
            cv.h[0] = (_Float16)(sc * acc[i][0]);
            cv.h[1] = (_Float16)(sc * acc[i][1]);
            cv.h[2] = (_Float16)(sc * acc[i][2]);
            cv.h[3] = (_Float16)(sc * acc[i][3]);
            *(uint2*)(out + (size_t)row * 32 + c4) = cv.u;
        }
    }
}

// ---------------- pull2 (fp16 g2): 8 lanes/node, natural order ----------------

__global__ void pull2_k(const __half* __restrict__ g, const int* __restrict__ rowoff,
                        const int* __restrict__ deg, const int* __restrict__ csr,
                        const float* __restrict__ dis, const float* __restrict__ b,
                        float* __restrict__ out, int n_nodes) {
    int gt = blockIdx.x * blockDim.x + threadIdx.x;
    int node = gt >> 3;
    int f0 = (gt & 7) * 4;
    if (node >= n_nodes) return;
    int beg = rowoff[node];
    int end = beg + deg[node];
    float dd = dis[node];

    float acc[4];
    {
        U2H4 v; v.u = *(const uint2*)(g + (size_t)node * 32 + f0);
        #pragma unroll
        for (int k = 0; k < 4; ++k) acc[k] = (float)v.h[k];
    }

    int j = beg;
    for (; j + 2 <= end; j += 2) {
        int s0 = csr[j];
        int s1 = csr[j + 1];
        U2H4 v0; v0.u = *(const uint2*)(g + (size_t)s0 * 32 + f0);
        U2H4 v1; v1.u = *(const uint2*)(g + (size_t)s1 * 32 + f0);
        #pragma unroll
        for (int k = 0; k < 4; ++k) acc[k] += (float)v0.h[k] + (float)v1.h[k];
    }
    if (j < end) {
        int s = csr[j];
        U2H4 v; v.u = *(const uint2*)(g + (size_t)s * 32 + f0);
        #pragma unroll
        for (int k = 0; k < 4; ++k) acc[k] += (float)v.h[k];
    }

    float4 bb = *(const float4*)(b + f0);
    *(float4*)(out + (size_t)node * 32 + f0) =
        make_float4(bb.x + dd * acc[0], bb.y + dd * acc[1],
                    bb.z + dd * acc[2], bb.w + dd * acc[3]);
}

// ---------------- GEMM3: g3[n][32] = dis[n] * (relu(in[n][32]) @ W[32][32]) ----------------

__global__ __launch_bounds__(256) void gemm3_k(const float* __restrict__ in,
                                               const float* __restrict__ W,
                                               const float* __restrict__ dis,
                                               float* __restrict__ out, int n_rows) {
    __shared__ float xs[64][36];
    __shared__ float wt[32][32];
    const int t = threadIdx.x;
    const int row0 = blockIdx.x * 64;

    #pragma unroll
    for (int i = 0; i < 2; ++i) {
        int q = t + i * 256;
        int row = q >> 3, c4 = (q & 7) * 4;
        float4 v = make_float4(0.f, 0.f, 0.f, 0.f);
        if (row0 + row < n_rows) {
            v = *(const float4*)(in + (size_t)(row0 + row) * 32 + c4);
            v.x = fmaxf(v.x, 0.f); v.y = fmaxf(v.y, 0.f);
            v.z = fmaxf(v.z, 0.f); v.w = fmaxf(v.w, 0.f);
        }
        *(float4*)&xs[row][c4] = v;
    }
    {
        int kk = t >> 3, c4 = (t & 7) * 4;
        *(float4*)&wt[kk][c4] = *(const float4*)(W + (size_t)kk * 32 + c4);
    }
    __syncthreads();

    const int c4 = (t & 7) * 4;
    const int r2 = (t >> 3) * 2;

    float acc[2][4];
    #pragma unroll
    for (int i = 0; i < 2; ++i)
        #pragma unroll
        for (int j = 0; j < 4; ++j) acc[i][j] = 0.f;

    #pragma unroll
    for (int k = 0; k < 32; ++k) {
        float x0 = xs[r2][k], x1 = xs[r2 + 1][k];
        float4 w = *(float4*)&wt[k][c4];
        acc[0][0] += x0 * w.x; acc[0][1] += x0 * w.y; acc[0][2] += x0 * w.z; acc[0][3] += x0 * w.w;
        acc[1][0] += x1 * w.x; acc[1][1] += x1 * w.y; acc[1][2] += x1 * w.z; acc[1][3] += x1 * w.w;
    }

    #pragma unroll
    for (int i = 0; i < 2; ++i) {
        int row = row0 + r2 + i;
        if (row < n_rows) {
            float sc = dis[row];
            *(float4*)(out + (size_t)row * 32 + c4) =
                make_float4(sc * acc[i][0], sc * acc[i][1], sc * acc[i][2], sc * acc[i][3]);
        }
    }
}

// ---------------- fused pull3 + head (sel nodes only): 8 lanes/sel-entry ----------------

__global__ void pull_head_k(const float* __restrict__ g, const int* __restrict__ rowoff,
                            const int* __restrict__ deg, const int* __restrict__ csr,
                            const float* __restrict__ dis, const float* __restrict__ b3,
                            const int* __restrict__ sel, const float* __restrict__ Wl,
                            const float* __restrict__ bl, float* __restrict__ out, int n_sel) {
    int gt = blockIdx.x * blockDim.x + threadIdx.x;
    int t = gt >> 3;
    int f0 = (gt & 7) * 4;
    if (t >= n_sel) return;
    int node = sel[t];
    int beg = rowoff[node];
    int end = beg + deg[node];
    float dd = dis[node];

    float4 acc = *(const float4*)(g + (size_t)node * 32 + f0);

    int j = beg;
    for (; j + 2 <= end; j += 2) {
        int s0 = csr[j];
        int s1 = csr[j + 1];
        float4 h0 = *(const float4*)(g + (size_t)s0 * 32 + f0);
        float4 h1 = *(const float4*)(g + (size_t)s1 * 32 + f0);
        acc.x += h0.x + h1.x;
        acc.y += h0.y + h1.y;
        acc.z += h0.z + h1.z;
        acc.w += h0.w + h1.w;
    }
    if (j < end) {
        int s = csr[j];
        float4 hs = *(const float4*)(g + (size_t)s * 32 + f0);
        acc.x += hs.x; acc.y += hs.y; acc.z += hs.z; acc.w += hs.w;
    }

    float4 bb = *(const float4*)(b3 + f0);
    float a0 = bb.x + dd * acc.x;
    float a1 = bb.y + dd * acc.y;
    float a2 = bb.z + dd * acc.z;
    float a3 = bb.w + dd * acc.w;

    float l0 = a0 * Wl[(f0 + 0) * 2] + a1 * Wl[(f0 + 1) * 2]
             + a2 * Wl[(f0 + 2) * 2] + a3 * Wl[(f0 + 3) * 2];
    float l1 = a0 * Wl[(f0 + 0) * 2 + 1] + a1 * Wl[(f0 + 1) * 2 + 1]
             + a2 * Wl[(f0 + 2) * 2 + 1] + a3 * Wl[(f0 + 3) * 2 + 1];
    #pragma unroll
    for (int m = 1; m < 8; m <<= 1) {
        l0 += __shfl_xor(l0, m);
        l1 += __shfl_xor(l1, m);
    }
    if ((gt & 7) == 0) {
        l0 += bl[0]; l1 += bl[1];
        float mx = fmaxf(l0, l1);
        float e0 = expf(l0 - mx), e1 = expf(l1 - mx);
        float s = e0 + e1;
        float ls = logf(s);
        *(float2*)(out + (size_t)t * 2) = make_float2((l0 - mx) - ls, (l1 - mx) - ls);
        *(float2*)(out + 2 * (size_t)n_sel + (size_t)t * 2) = make_float2(e0 / s, e1 / s);
    }
}

// ---------------- launch ----------------

extern "C" void kernel_launch(void* const* d_in, const int* in_sizes, int n_in,
                              void* d_out, int out_size, void* d_ws, size_t ws_size,
                              hipStream_t stream) {
    const float* x  = (const float*)d_in[0];
    const int* edge = (const int*)d_in[1];
    const int* sel  = (const int*)d_in[2];
    const float* W1 = (const float*)d_in[4];
    const float* b1 = (const float*)d_in[5];
    const float* W2 = (const float*)d_in[6];
    const float* b2 = (const float*)d_in[7];
    const float* W3 = (const float*)d_in[8];
    const float* b3 = (const float*)d_in[9];
    const float* Wl = (const float*)d_in[10];
    const float* bl = (const float*)d_in[11];
    float* out = (float*)d_out;

    const int n_nodes = in_sizes[0] / F_IN;
    const int n_edges = in_sizes[1] / 2;
    const int n_sel   = in_sizes[2];
    const int* srcv = edge;
    const int* dstv = edge + n_edges;
    const int n_buckets = (n_nodes + NPB - 1) / NPB;   // 196
    const int n_gh = n_buckets * NBK;                  // 50176

    char* ws = (char*)d_ws;
    int*       deg      = (int*)ws;       ws += alignup((size_t)n_nodes * 4);
    float*     dis      = (float*)ws;     ws += alignup((size_t)n_nodes * 4);
    int*       rowoff   = (int*)ws;       ws += alignup((size_t)n_nodes * 4);
    int*       ghist    = (int*)ws;       ws += alignup((size_t)n_gh * 4);
    int*       goff     = (int*)ws;       ws += alignup((size_t)n_gh * 4);
    int*       partial2 = (int*)ws;       ws += alignup(1024);
    _Float16*  Wt       = (_Float16*)ws;  ws += alignup(128 * 128 * 2);
    unsigned*  tmp      = (unsigned*)ws;  ws += alignup((size_t)n_edges * 4);
    int*       csr      = (int*)ws;       ws += alignup((size_t)n_edges * 4);
    char*      bufA     = ws;             ws += alignup((size_t)n_nodes * HID * 4);
    char*      bufB     = ws;

    const int B = 256;
    #define GRD(n) (((n) + B - 1) / B)
    const int nblk2 = GRD(n_gh);   // 196
    const int gemm_blocks = (n_nodes + 63) / 64;   // 782

    // CSR build prefix
    hist_k<<<NBK, 1024, 0, stream>>>(dstv, ghist, W1, Wt, n_edges, n_buckets);
    scan_block_k<<<nblk2, B, 0, stream>>>(ghist, goff, partial2, n_gh);
    scan_partials_k<<<1, B, 0, stream>>>(partial2, nblk2);

    // fused: edge partition (256 blocks) ∥ gemm1 unscaled fp16 (782 blocks)
    fused_scatter_gemm1_k<<<NBK + gemm_blocks, 1024, 0, stream>>>(
        srcv, dstv, goff, partial2, tmp, n_edges, n_buckets,
        x, Wt, (__half*)bufA, n_nodes);

    // finalize CSR (deg/dis/rowoff/csr)
    binC_k<<<n_buckets, NPB, 0, stream>>>(tmp, goff, partial2, deg, dis, rowoff, csr,
                                          n_nodes, n_edges, n_buckets);

    // layer 1 aggregate: agg1relu fp16 = relu(b1 + dis*(dis*h1 + sum dis[s]*h1[s]))
    pull1_k<<<GRD(n_nodes * 16), B, 0, stream>>>((const __half*)bufA, rowoff, deg, csr,
                                                 dis, b1, (__half*)bufB, n_nodes);

    // layer 2: g2 fp16 = dis*(agg1relu@W2); agg2 fp32
    gemm2_k<<<gemm_blocks, B, 0, stream>>>((const __half*)bufB, W2, dis, (__half*)bufA, n_nodes);
    pull2_k<<<GRD(n_nodes * 8), B, 0, stream>>>((const __half*)bufA, rowoff, deg, csr,
                                                dis, b2, (float*)bufB, n_nodes);

    // layer 3: g3 fp32; pull+head on selected nodes only
    gemm3_k<<<gemm_blocks, B, 0, stream>>>((const float*)bufB, W3, dis, (float*)bufA, n_nodes);
    pull_head_k<<<GRD(n_sel * 8), B, 0, stream>>>((const float*)bufA, rowoff, deg, csr, dis, b3,
                                                  sel, Wl, bl, out, n_sel);

    #undef GRD
}

// Round 19
// 125.544 us; speedup vs baseline: 1.1355x; 1.0321x over previous
//
#include <hip/hip_runtime.h>
#include <hip/hip_fp16.h>

#define F_IN 128
#define HID 128
#define HID4 32
#define NPB 256          // nodes per CSR bucket
#define SRC_BITS 17      // n_nodes = 50000 < 2^17
#define NBK 256          // partition chunks/blocks (== 256 so partial idx == bucket idx)
#define MAXBUCKET 256    // LDS counter array size (n_buckets = 196)

static inline size_t alignup(size_t x) { return (x + 255) & ~(size_t)255; }

typedef _Float16 half8 __attribute__((ext_vector_type(8)));
typedef float f32x4 __attribute__((ext_vector_type(4)));

union F4H8 { float4 f; __half2 h[4]; };   // 8 halfs = 16 B
union U2H4 { uint2 u; _Float16 h[4]; };   // 4 halfs = 8 B

// ---------------- pass 1: bucket histogram (+ folded W1 transpose to fp16) ----------------

__global__ __launch_bounds__(1024) void hist_k(const int* __restrict__ dst,
                                               int* __restrict__ ghist,
                                               const float* __restrict__ W1,
                                               _Float16* __restrict__ Wt,
                                               int ne, int n_buckets) {
    __shared__ int h[MAXBUCKET];
    const int t = threadIdx.x;
    if (blockIdx.x < 16) {
        int q = blockIdx.x * 1024 + t;
        int k = q >> 7, n = q & 127;
        Wt[n * 128 + k] = (_Float16)W1[q];
    }
    for (int b = t; b < n_buckets; b += 1024) h[b] = 0;
    __syncthreads();
    const int chunk = (ne + NBK - 1) / NBK;
    const int beg = blockIdx.x * chunk;
    const int end = min(ne, beg + chunk);
    for (int e = beg + t; e < end; e += 1024)
        atomicAdd(&h[dst[e] / NPB], 1);
    __syncthreads();
    for (int b = t; b < n_buckets; b += 1024)
        ghist[(size_t)b * NBK + blockIdx.x] = h[b];
}

// ---------------- 2-level exclusive scan ----------------

__global__ void scan_block_k(const int* __restrict__ in, int* __restrict__ out,
                             int* __restrict__ partials, int n) {
    __shared__ int tmp[256];
    int i = blockIdx.x * 256 + threadIdx.x;
    int v = (i < n) ? in[i] : 0;
    tmp[threadIdx.x] = v;
    __syncthreads();
    for (int off = 1; off < 256; off <<= 1) {
        int t = (threadIdx.x >= off) ? tmp[threadIdx.x - off] : 0;
        __syncthreads();
        tmp[threadIdx.x] += t;
        __syncthreads();
    }
    if (i < n) out[i] = tmp[threadIdx.x] - v;
    if (threadIdx.x == 255) partials[blockIdx.x] = tmp[255];
}

__global__ void scan_partials_k(int* __restrict__ partials, int nb) {
    __shared__ int tmp[256];
    int v = (threadIdx.x < nb) ? partials[threadIdx.x] : 0;
    tmp[threadIdx.x] = v;
    __syncthreads();
    for (int off = 1; off < 256; off <<= 1) {
        int t = (threadIdx.x >= off) ? tmp[threadIdx.x - off] : 0;
        __syncthreads();
        tmp[threadIdx.x] += t;
        __syncthreads();
    }
    if (threadIdx.x < nb) partials[threadIdx.x] = tmp[threadIdx.x] - v;
}

// ---------------- FUSED: scatter2 (blocks 0..NBK) ∥ gemm1 unscaled (blocks NBK..) ----------------

__global__ __launch_bounds__(1024) void fused_scatter_gemm1_k(
        const int* __restrict__ src, const int* __restrict__ dst,
        const int* __restrict__ goff, const int* __restrict__ partial2,
        unsigned* __restrict__ tmp, int ne, int n_buckets,
        const float* __restrict__ in, const _Float16* __restrict__ Wt,
        __half* __restrict__ hout, int n_rows) {
    __shared__ int cur[MAXBUCKET];
    __shared__ _Float16 xs[64][136];
    const int t = threadIdx.x;

    if (blockIdx.x < NBK) {
        for (int b = t; b < n_buckets; b += 1024)
            cur[b] = goff[(size_t)b * NBK + blockIdx.x] + partial2[b];
        __syncthreads();
        const int chunk = (ne + NBK - 1) / NBK;
        const int beg = blockIdx.x * chunk;
        const int end = min(ne, beg + chunk);
        for (int e = beg + t; e < end; e += 1024) {
            int d = dst[e];
            int s = src[e];
            int pos = atomicAdd(&cur[d / NPB], 1);
            tmp[pos] = ((unsigned)(d & (NPB - 1)) << SRC_BITS) | (unsigned)s;
        }
        return;
    }

    const int row0 = (blockIdx.x - NBK) * 64;

    #pragma unroll
    for (int i = 0; i < 2; ++i) {
        int q = t + i * 1024;
        int row = q >> 5, c4 = (q & 31) * 4;
        float4 v = make_float4(0.f, 0.f, 0.f, 0.f);
        if (row0 + row < n_rows) v = *(const float4*)(in + (size_t)(row0 + row) * 128 + c4);
        U2H4 cv;
        cv.h[0] = (_Float16)v.x; cv.h[1] = (_Float16)v.y;
        cv.h[2] = (_Float16)v.z; cv.h[3] = (_Float16)v.w;
        *(uint2*)&xs[row][c4] = cv.u;
    }
    __syncthreads();

    const int lane = t & 63;
    const int wave = t >> 6;            // 0..15
    const int r0 = (wave & 3) * 16;     // row tile
    const int cg = (wave >> 2) * 32;    // col group (32 cols)
    const int lrow = lane & 15;
    const int kgrp = (lane >> 4) * 8;

    f32x4 acc[2];
    acc[0] = (f32x4){0.f, 0.f, 0.f, 0.f};
    acc[1] = (f32x4){0.f, 0.f, 0.f, 0.f};

    #pragma unroll
    for (int kk = 0; kk < 4; ++kk) {
        const int k0 = kk * 32 + kgrp;
        half8 a = *(const half8*)&xs[r0 + lrow][k0];
        #pragma unroll
        for (int ct = 0; ct < 2; ++ct) {
            half8 b = *(const half8*)(Wt + (size_t)(cg + ct * 16 + lrow) * 128 + k0);
            acc[ct] = __builtin_amdgcn_mfma_f32_16x16x32_f16(a, b, acc[ct], 0, 0, 0);
        }
    }

    #pragma unroll
    for (int i = 0; i < 4; ++i) {
        int row = row0 + r0 + (lane >> 4) * 4 + i;
        if (row < n_rows) {
            __half* p = hout + (size_t)row * 128 + cg + lrow;
            p[0]  = __float2half(acc[0][i]);
            p[16] = __float2half(acc[1][i]);
        }
    }
}

// ---------------- pass 3: per-bucket deg/dis/rowoff + final CSR placement (1024 thr) ----------------

__global__ __launch_bounds__(1024) void binC_k(const unsigned* __restrict__ tmp,
                                               const int* __restrict__ goff,
                                               const int* __restrict__ partial2,
                                               int* __restrict__ deg, float* __restrict__ dis,
                                               int* __restrict__ rowoff, int* __restrict__ csr,
                                               int n_nodes, int ne, int n_buckets) {
    __shared__ int cnt[NPB];
    __shared__ int sc[NPB];
    const int t = threadIdx.x;
    const int bid = blockIdx.x;
    const int base = goff[(size_t)bid * NBK] + partial2[bid];
    const int end = (bid + 1 < n_buckets) ? goff[(size_t)(bid + 1) * NBK] + partial2[bid + 1] : ne;

    if (t < NPB) cnt[t] = 0;
    __syncthreads();
    for (int j = base + t; j < end; j += 1024)
        atomicAdd(&cnt[tmp[j] >> SRC_BITS], 1);   // LDS atomic, per-node degree
    __syncthreads();

    int mydeg = (t < NPB) ? cnt[t] : 0;
    if (t < NPB) sc[t] = mydeg;
    __syncthreads();
    for (int off = 1; off < NPB; off <<= 1) {     // Hillis-Steele (first 256 lanes)
        int v = (t >= off && t < NPB) ? sc[t - off] : 0;
        __syncthreads();
        if (t < NPB) sc[t] += v;
        __syncthreads();
    }
    if (t < NPB) {
        int excl = sc[t] - mydeg;
        int node = bid * NPB + t;
        if (node < n_nodes) {
            deg[node] = mydeg;
            dis[node] = rsqrtf((float)(mydeg + 1));
            rowoff[node] = base + excl;
        }
        cnt[t] = base + excl;                     // placement cursor
    }
    __syncthreads();
    for (int j = base + t; j < end; j += 1024) {
        unsigned e = tmp[j];
        int ld = e >> SRC_BITS;
        int s  = e & ((1u << SRC_BITS) - 1);
        int pos = atomicAdd(&cnt[ld], 1);
        csr[pos] = s;
    }
}

// ---------------- pull1: 16 lanes/node; h1 unscaled -> gathers dis[s]; emits fp16 relu(agg1) ----------------

__global__ void pull1_k(const __half* __restrict__ g, const int* __restrict__ rowoff,
                        const int* __restrict__ deg, const int* __restrict__ csr,
                        const float* __restrict__ dis, const float* __restrict__ b,
                        __half* __restrict__ out, int n_nodes) {
    int gt = blockIdx.x * blockDim.x + threadIdx.x;
    int node = gt >> 4;
    int f0 = (gt & 15) * 8;
    if (node >= n_nodes) return;
    int beg = rowoff[node];
    int end = beg + deg[node];
    float dd = dis[node];

    float acc[8];
    {
        F4H8 v; v.f = *(const float4*)(g + (size_t)node * 128 + f0);
        #pragma unroll
        for (int k = 0; k < 4; ++k) {
            float2 p = __half22float2(v.h[k]);
            acc[2 * k] = dd * p.x; acc[2 * k + 1] = dd * p.y;
        }
    }

    int j = beg;
    for (; j + 2 <= end; j += 2) {
        int s0 = csr[j];
        int s1 = csr[j + 1];
        float w0 = dis[s0];
        float w1 = dis[s1];
        F4H8 v0; v0.f = *(const float4*)(g + (size_t)s0 * 128 + f0);
        F4H8 v1; v1.f = *(const float4*)(g + (size_t)s1 * 128 + f0);
        #pragma unroll
        for (int k = 0; k < 4; ++k) {
            float2 p0 = __half22float2(v0.h[k]);
            float2 p1 = __half22float2(v1.h[k]);
            acc[2 * k]     += w0 * p0.x + w1 * p1.x;
            acc[2 * k + 1] += w0 * p0.y + w1 * p1.y;
        }
    }
    if (j < end) {
        int s = csr[j];
        float w = dis[s];
        F4H8 v; v.f = *(const float4*)(g + (size_t)s * 128 + f0);
        #pragma unroll
        for (int k = 0; k < 4; ++k) {
            float2 p = __half22float2(v.h[k]);
            acc[2 * k] += w * p.x; acc[2 * k + 1] += w * p.y;
        }
    }

    float4 b0 = *(const float4*)(b + f0);
    float4 b1 = *(const float4*)(b + f0 + 4);
    F4H8 o;
    o.h[0] = __floats2half2_rn(fmaxf(b0.x + dd * acc[0], 0.f), fmaxf(b0.y + dd * acc[1], 0.f));
    o.h[1] = __floats2half2_rn(fmaxf(b0.z + dd * acc[2], 0.f), fmaxf(b0.w + dd * acc[3], 0.f));
    o.h[2] = __floats2half2_rn(fmaxf(b1.x + dd * acc[4], 0.f), fmaxf(b1.y + dd * acc[5], 0.f));
    o.h[3] = __floats2half2_rn(fmaxf(b1.z + dd * acc[6], 0.f), fmaxf(b1.w + dd * acc[7], 0.f));
    *(float4*)(out + (size_t)node * 128 + f0) = o.f;
}

// ---------------- GEMM2: g2[n][32] (fp16) = dis[n] * (agg1relu[n][128] @ W[128][32]) ----------------

__global__ __launch_bounds__(256) void gemm2_k(const __half* __restrict__ in,
                                               const float* __restrict__ W,
                                               const float* __restrict__ dis,
                                               __half* __restrict__ out, int n_rows) {
    __shared__ float xs[64][132];
    __shared__ float wt[128][32];
    const int t = threadIdx.x;
    const int row0 = blockIdx.x * 64;

    #pragma unroll
    for (int i = 0; i < 4; ++i) {
        int q = t + i * 256;
        int row = q >> 4, c8 = (q & 15) * 8;
        F4H8 v;
        v.f = make_float4(0.f, 0.f, 0.f, 0.f);
        if (row0 + row < n_rows)
            v.f = *(const float4*)(in + (size_t)(row0 + row) * 128 + c8);
        #pragma unroll
        for (int k = 0; k < 4; ++k) {
            float2 p = __half22float2(v.h[k]);
            xs[row][c8 + 2 * k] = p.x;
            xs[row][c8 + 2 * k + 1] = p.y;
        }
    }
    #pragma unroll
    for (int i = 0; i < 4; ++i) {
        int q = t + i * 256;
        int kk = q >> 3, c4 = (q & 7) * 4;
        *(float4*)&wt[kk][c4] = *(const float4*)(W + (size_t)kk * 32 + c4);
    }
    __syncthreads();

    const int c4 = (t & 7) * 4;
    const int r2 = (t >> 3) * 2;

    float acc[2][4];
    #pragma unroll
    for (int i = 0; i < 2; ++i)
        #pragma unroll
        for (int j = 0; j < 4; ++j) acc[i][j] = 0.f;

    #pragma unroll 4
    for (int k = 0; k < 128; ++k) {
        float x0 = xs[r2][k], x1 = xs[r2 + 1][k];
        float4 w = *(float4*)&wt[k][c4];
        acc[0][0] += x0 * w.x; acc[0][1] += x0 * w.y; acc[0][2] += x0 * w.z; acc[0][3] += x0 * w.w;
        acc[1][0] += x1 * w.x; acc[1][1] += x1 * w.y; acc[1][2] += x1 * w.z; acc[1][3] += x1 * w.w;
    }

    #pragma unroll
    for (int i = 0; i < 2; ++i) {
        int row = row0 + r2 + i;
        if (row < n_rows) {
            float sc = dis[row];
            U2H4 cv;
            cv.h[0] = (_Float16)(sc * acc[i][0]);
            cv.h[1] = (_Float16)(sc * acc[i][1]);
            cv.h[2] = (_Float16)(sc * acc[i][2]);
            cv.h[3] = (_Float16)(sc * acc[i][3]);
            *(uint2*)(out + (size_t)row * 32 + c4) = cv.u;
        }
    }
}

// ---------------- pull2 (fp16 g2): 8 lanes/node, natural order ----------------

__global__ void pull2_k(const __half* __restrict__ g, const int* __restrict__ rowoff,
                        const int* __restrict__ deg, const int* __restrict__ csr,
                        const float* __restrict__ dis, const float* __restrict__ b,
                        float* __restrict__ out, int n_nodes) {
    int gt = blockIdx.x * blockDim.x + threadIdx.x;
    int node = gt >> 3;
    int f0 = (gt & 7) * 4;
    if (node >= n_nodes) return;
    int beg = rowoff[node];
    int end = beg + deg[node];
    float dd = dis[node];

    float acc[4];
    {
        U2H4 v; v.u = *(const uint2*)(g + (size_t)node * 32 + f0);
        #pragma unroll
        for (int k = 0; k < 4; ++k) acc[k] = (float)v.h[k];
    }

    int j = beg;
    for (; j + 2 <= end; j += 2) {
        int s0 = csr[j];
        int s1 = csr[j + 1];
        U2H4 v0; v0.u = *(const uint2*)(g + (size_t)s0 * 32 + f0);
        U2H4 v1; v1.u = *(const uint2*)(g + (size_t)s1 * 32 + f0);
        #pragma unroll
        for (int k = 0; k < 4; ++k) acc[k] += (float)v0.h[k] + (float)v1.h[k];
    }
    if (j < end) {
        int s = csr[j];
        U2H4 v; v.u = *(const uint2*)(g + (size_t)s * 32 + f0);
        #pragma unroll
        for (int k = 0; k < 4; ++k) acc[k] += (float)v.h[k];
    }

    float4 bb = *(const float4*)(b + f0);
    *(float4*)(out + (size_t)node * 32 + f0) =
        make_float4(bb.x + dd * acc[0], bb.y + dd * acc[1],
                    bb.z + dd * acc[2], bb.w + dd * acc[3]);
}

// ---------------- GEMM3: g3[n][32] = dis[n] * (relu(in[n][32]) @ W[32][32]) ----------------

__global__ __launch_bounds__(256) void gemm3_k(const float* __restrict__ in,
                                               const float* __restrict__ W,
                                               const float* __restrict__ dis,
                                               float* __restrict__ out, int n_rows) {
    __shared__ float xs[64][36];
    __shared__ float wt[32][32];
    const int t = threadIdx.x;
    const int row0 = blockIdx.x * 64;

    #pragma unroll
    for (int i = 0; i < 2; ++i) {
        int q = t + i * 256;
        int row = q >> 3, c4 = (q & 7) * 4;
        float4 v = make_float4(0.f, 0.f, 0.f, 0.f);
        if (row0 + row < n_rows) {
            v = *(const float4*)(in + (size_t)(row0 + row) * 32 + c4);
            v.x = fmaxf(v.x, 0.f); v.y = fmaxf(v.y, 0.f);
            v.z = fmaxf(v.z, 0.f); v.w = fmaxf(v.w, 0.f);
        }
        *(float4*)&xs[row][c4] = v;
    }
    {
        int kk = t >> 3, c4 = (t & 7) * 4;
        *(float4*)&wt[kk][c4] = *(const float4*)(W + (size_t)kk * 32 + c4);
    }
    __syncthreads();

    const int c4 = (t & 7) * 4;
    const int r2 = (t >> 3) * 2;

    float acc[2][4];
    #pragma unroll
    for (int i = 0; i < 2; ++i)
        #pragma unroll
        for (int j = 0; j < 4; ++j) acc[i][j] = 0.f;

    #pragma unroll
    for (int k = 0; k < 32; ++k) {
        float x0 = xs[r2][k], x1 = xs[r2 + 1][k];
        float4 w = *(float4*)&wt[k][c4];
        acc[0][0] += x0 * w.x; acc[0][1] += x0 * w.y; acc[0][2] += x0 * w.z; acc[0][3] += x0 * w.w;
        acc[1][0] += x1 * w.x; acc[1][1] += x1 * w.y; acc[1][2] += x1 * w.z; acc[1][3] += x1 * w.w;
    }

    #pragma unroll
    for (int i = 0; i < 2; ++i) {
        int row = row0 + r2 + i;
        if (row < n_rows) {
            float sc = dis[row];
            *(float4*)(out + (size_t)row * 32 + c4) =
                make_float4(sc * acc[i][0], sc * acc[i][1], sc * acc[i][2], sc * acc[i][3]);
        }
    }
}

// ---------------- fused pull3 + head (sel nodes only): 8 lanes/sel-entry ----------------

__global__ void pull_head_k(const float* __restrict__ g, const int* __restrict__ rowoff,
                            const int* __restrict__ deg, const int* __restrict__ csr,
                            const float* __restrict__ dis, const float* __restrict__ b3,
                            const int* __restrict__ sel, const float* __restrict__ Wl,
                            const float* __restrict__ bl, float* __restrict__ out, int n_sel) {
    int gt = blockIdx.x * blockDim.x + threadIdx.x;
    int t = gt >> 3;
    int f0 = (gt & 7) * 4;
    if (t >= n_sel) return;
    int node = sel[t];
    int beg = rowoff[node];
    int end = beg + deg[node];
    float dd = dis[node];

    float4 acc = *(const float4*)(g + (size_t)node * 32 + f0);

    int j = beg;
    for (; j + 2 <= end; j += 2) {
        int s0 = csr[j];
        int s1 = csr[j + 1];
        float4 h0 = *(const float4*)(g + (size_t)s0 * 32 + f0);
        float4 h1 = *(const float4*)(g + (size_t)s1 * 32 + f0);
        acc.x += h0.x + h1.x;
        acc.y += h0.y + h1.y;
        acc.z += h0.z + h1.z;
        acc.w += h0.w + h1.w;
    }
    if (j < end) {
        int s = csr[j];
        float4 hs = *(const float4*)(g + (size_t)s * 32 + f0);
        acc.x += hs.x; acc.y += hs.y; acc.z += hs.z; acc.w += hs.w;
    }

    float4 bb = *(const float4*)(b3 + f0);
    float a0 = bb.x + dd * acc.x;
    float a1 = bb.y + dd * acc.y;
    float a2 = bb.z + dd * acc.z;
    float a3 = bb.w + dd * acc.w;

    float l0 = a0 * Wl[(f0 + 0) * 2] + a1 * Wl[(f0 + 1) * 2]
             + a2 * Wl[(f0 + 2) * 2] + a3 * Wl[(f0 + 3) * 2];
    float l1 = a0 * Wl[(f0 + 0) * 2 + 1] + a1 * Wl[(f0 + 1) * 2 + 1]
             + a2 * Wl[(f0 + 2) * 2 + 1] + a3 * Wl[(f0 + 3) * 2 + 1];
    #pragma unroll
    for (int m = 1; m < 8; m <<= 1) {
        l0 += __shfl_xor(l0, m);
        l1 += __shfl_xor(l1, m);
    }
    if ((gt & 7) == 0) {
        l0 += bl[0]; l1 += bl[1];
        float mx = fmaxf(l0, l1);
        float e0 = expf(l0 - mx), e1 = expf(l1 - mx);
        float s = e0 + e1;
        float ls = logf(s);
        *(float2*)(out + (size_t)t * 2) = make_float2((l0 - mx) - ls, (l1 - mx) - ls);
        *(float2*)(out + 2 * (size_t)n_sel + (size_t)t * 2) = make_float2(e0 / s, e1 / s);
    }
}

// ---------------- launch ----------------

extern "C" void kernel_launch(void* const* d_in, const int* in_sizes, int n_in,
                              void* d_out, int out_size, void* d_ws, size_t ws_size,
                              hipStream_t stream) {
    const float* x  = (const float*)d_in[0];
    const int* edge = (const int*)d_in[1];
    const int* sel  = (const int*)d_in[2];
    const float* W1 = (const float*)d_in[4];
    const float* b1 = (const float*)d_in[5];
    const float* W2 = (const float*)d_in[6];
    const float* b2 = (const float*)d_in[7];
    const float* W3 = (const float*)d_in[8];
    const float* b3 = (const float*)d_in[9];
    const float* Wl = (const float*)d_in[10];
    const float* bl = (const float*)d_in[11];
    float* out = (float*)d_out;

    const int n_nodes = in_sizes[0] / F_IN;
    const int n_edges = in_sizes[1] / 2;
    const int n_sel   = in_sizes[2];
    const int* srcv = edge;
    const int* dstv = edge + n_edges;
    const int n_buckets = (n_nodes + NPB - 1) / NPB;   // 196
    const int n_gh = n_buckets * NBK;                  // 50176

    char* ws = (char*)d_ws;
    int*       deg      = (int*)ws;       ws += alignup((size_t)n_nodes * 4);
    float*     dis      = (float*)ws;     ws += alignup((size_t)n_nodes * 4);
    int*       rowoff   = (int*)ws;       ws += alignup((size_t)n_nodes * 4);
    int*       ghist    = (int*)ws;       ws += alignup((size_t)n_gh * 4);
    int*       goff     = (int*)ws;       ws += alignup((size_t)n_gh * 4);
    int*       partial2 = (int*)ws;       ws += alignup(1024);
    _Float16*  Wt       = (_Float16*)ws;  ws += alignup(128 * 128 * 2);
    unsigned*  tmp      = (unsigned*)ws;  ws += alignup((size_t)n_edges * 4);
    int*       csr      = (int*)ws;       ws += alignup((size_t)n_edges * 4);
    char*      bufA     = ws;             ws += alignup((size_t)n_nodes * HID * 4);
    char*      bufB     = ws;

    const int B = 256;
    #define GRD(n) (((n) + B - 1) / B)
    const int nblk2 = GRD(n_gh);   // 196
    const int gemm_blocks = (n_nodes + 63) / 64;   // 782

    // CSR build prefix
    hist_k<<<NBK, 1024, 0, stream>>>(dstv, ghist, W1, Wt, n_edges, n_buckets);
    scan_block_k<<<nblk2, B, 0, stream>>>(ghist, goff, partial2, n_gh);
    scan_partials_k<<<1, B, 0, stream>>>(partial2, nblk2);

    // fused: edge partition (256 blocks) ∥ gemm1 unscaled fp16 (782 blocks)
    fused_scatter_gemm1_k<<<NBK + gemm_blocks, 1024, 0, stream>>>(
        srcv, dstv, goff, partial2, tmp, n_edges, n_buckets,
        x, Wt, (__half*)bufA, n_nodes);

    // finalize CSR (deg/dis/rowoff/csr) — 1024 threads/bucket
    binC_k<<<n_buckets, 1024, 0, stream>>>(tmp, goff, partial2, deg, dis, rowoff, csr,
                                           n_nodes, n_edges, n_buckets);

    // layer 1 aggregate: agg1relu fp16 = relu(b1 + dis*(dis*h1 + sum dis[s]*h1[s]))
    pull1_k<<<GRD(n_nodes * 16), B, 0, stream>>>((const __half*)bufA, rowoff, deg, csr,
                                                 dis, b1, (__half*)bufB, n_nodes);

    // layer 2: g2 fp16 = dis*(agg1relu@W2); agg2 fp32
    gemm2_k<<<gemm_blocks, B, 0, stream>>>((const __half*)bufB, W2, dis, (__half*)bufA, n_nodes);
    pull2_k<<<GRD(n_nodes * 8), B, 0, stream>>>((const __half*)bufA, rowoff, deg, csr,
                                                dis, b2, (float*)bufB, n_nodes);

    // layer 3: g3 fp32; pull+head on selected nodes only
    gemm3_k<<<gemm_blocks, B, 0, stream>>>((const float*)bufB, W3, dis, (float*)bufA, n_nodes);
    pull_head_k<<<GRD(n_sel * 8), B, 0, stream>>>((const float*)bufA, rowoff, deg, csr, dis, b3,
                                                  sel, Wl, bl, out, n_sel);

    #undef GRD
}